// Round 1
// baseline (2032.056 us; speedup 1.0000x reference)
//
#include <hip/hip_runtime.h>

#define CIN 64
#define HH 112
#define WW 112
#define COUT 128
#define NBUCKETS 16
#define TILE 16
#define COUT_TILE 16

// ---------------- prep: min/max + sequential bucket hashing ----------------
__global__ __launch_bounds__(1024) void hashedconv_prep_kernel(
    const float* __restrict__ W, const float* __restrict__ hashed_w,
    float* __restrict__ hw_out) {
  const int NW = COUT * CIN * 9;  // 73728
  int tid = threadIdx.x;

  float vmin = 1e30f, vmax = -1e30f;
  for (int i = tid; i < NW; i += 1024) {
    float v = W[i];
    vmin = fminf(vmin, v);
    vmax = fmaxf(vmax, v);
  }
  // wave (64-lane) reduce
  #pragma unroll
  for (int off = 32; off > 0; off >>= 1) {
    vmin = fminf(vmin, __shfl_down(vmin, off, 64));
    vmax = fmaxf(vmax, __shfl_down(vmax, off, 64));
  }
  __shared__ float smin[16], smax[16];
  __shared__ float s_wmin, s_step;
  __shared__ float hv[NBUCKETS];
  int wave = tid >> 6, lane = tid & 63;
  if (lane == 0) { smin[wave] = vmin; smax[wave] = vmax; }
  if (tid < NBUCKETS) hv[tid] = hashed_w[tid];
  __syncthreads();
  if (tid == 0) {
    float m = smin[0], M = smax[0];
    #pragma unroll
    for (int i = 1; i < 16; ++i) { m = fminf(m, smin[i]); M = fmaxf(M, smax[i]); }
    s_wmin = m;
    s_step = (M - m) / (float)NBUCKETS;  // matches jnp fp32: (wmax-wmin)/BUCKETS
  }
  __syncthreads();
  float wmin = s_wmin, step = s_step;

  for (int i = tid; i < NW; i += 1024) {
    float v = W[i];
    // faithful sequential in-place semantics: replaced values re-compared
    #pragma unroll
    for (int b = 0; b < NBUCKETS; ++b) {
      float thr = (float)(b + 1) * step + wmin;  // two fp32 ops, same as jnp
      if (v > thr) v = hv[b];
    }
    hw_out[i] = v;
  }
}

// ---------------- fused dual conv (original + hashed weights) ----------------
__global__ __launch_bounds__(256) void hashedconv_conv_kernel(
    const float* __restrict__ x, const float* __restrict__ W,
    const float* __restrict__ HW, const float* __restrict__ b,
    const float* __restrict__ b2, float* __restrict__ out,
    int N, size_t out_half) {
  // grid: (49 tiles, COUT/COUT_TILE, N); block: 256 = 16x16 pixels
  const int n = blockIdx.z;
  const int co0 = blockIdx.y * COUT_TILE;
  const int tiles_w = WW / TILE;  // 7
  const int th = blockIdx.x / tiles_w;
  const int tw = blockIdx.x % tiles_w;
  const int h0 = th * TILE, w0 = tw * TILE;

  __shared__ float xs[TILE + 2][TILE + 2];

  const int tid = threadIdx.x;
  const int lw = tid & (TILE - 1);
  const int lh = tid >> 4;

  float acc[COUT_TILE], acc2[COUT_TILE];
  #pragma unroll
  for (int i = 0; i < COUT_TILE; ++i) { acc[i] = 0.f; acc2[i] = 0.f; }

  const float* xn = x + (size_t)n * CIN * HH * WW;

  for (int cin = 0; cin < CIN; ++cin) {
    const float* xc = xn + (size_t)cin * HH * WW;
    // stage 18x18 input tile (zero-padded at borders)
    for (int i = tid; i < 18 * 18; i += 256) {
      int r = i / 18, c = i - r * 18;
      int gh = h0 - 1 + r, gw = w0 - 1 + c;
      float v = 0.f;
      if (gh >= 0 && gh < HH && gw >= 0 && gw < WW) v = xc[gh * WW + gw];
      xs[r][c] = v;
    }
    __syncthreads();

    float xr[9];
    #pragma unroll
    for (int dh = 0; dh < 3; ++dh)
      #pragma unroll
      for (int dw = 0; dw < 3; ++dw)
        xr[dh * 3 + dw] = xs[lh + dh][lw + dw];

    // weights: block-uniform addresses -> scalar loads
    const float* wbase  = W  + ((size_t)co0 * CIN + cin) * 9;
    const float* wbase2 = HW + ((size_t)co0 * CIN + cin) * 9;
    #pragma unroll
    for (int co = 0; co < COUT_TILE; ++co) {
      const float* w1 = wbase  + (size_t)co * CIN * 9;
      const float* w2 = wbase2 + (size_t)co * CIN * 9;
      float a0 = acc[co], a1 = acc2[co];
      #pragma unroll
      for (int k = 0; k < 9; ++k) {
        a0 = fmaf(w1[k], xr[k], a0);
        a1 = fmaf(w2[k], xr[k], a1);
      }
      acc[co] = a0; acc2[co] = a1;
    }
    __syncthreads();
  }

  // epilogue: add bias, write both outputs
  const int h = h0 + lh, w = w0 + lw;
  const size_t HWs = (size_t)HH * WW;
  const size_t base = (size_t)n * COUT * HWs + (size_t)h * WW + w;
  #pragma unroll
  for (int co = 0; co < COUT_TILE; ++co) {
    out[base + (size_t)(co0 + co) * HWs]            = acc[co]  + b[co0 + co];
    out[base + (size_t)(co0 + co) * HWs + out_half] = acc2[co] + b2[co0 + co];
  }
}

extern "C" void kernel_launch(void* const* d_in, const int* in_sizes, int n_in,
                              void* d_out, int out_size, void* d_ws, size_t ws_size,
                              hipStream_t stream) {
  const float* x      = (const float*)d_in[0];
  const float* W      = (const float*)d_in[1];
  const float* b      = (const float*)d_in[2];
  const float* b2     = (const float*)d_in[3];
  const float* hashed = (const float*)d_in[4];
  float* out = (float*)d_out;
  float* hw  = (float*)d_ws;  // 73728 floats scratch

  const int N = in_sizes[0] / (CIN * HH * WW);
  const size_t out_half = (size_t)N * COUT * HH * WW;

  hipLaunchKernelGGL(hashedconv_prep_kernel, dim3(1), dim3(1024), 0, stream,
                     W, hashed, hw);

  dim3 grid((HH / TILE) * (WW / TILE), COUT / COUT_TILE, N);
  hipLaunchKernelGGL(hashedconv_conv_kernel, grid, dim3(256), 0, stream,
                     x, W, hw, b, b2, out, N, out_half);
}

// Round 2
// 458.988 us; speedup vs baseline: 4.4273x; 4.4273x over previous
//
#include <hip/hip_runtime.h>

#define CIN 64
#define HHW 112
#define COUT 128
#define KTOT 576      // 9 offsets * 64 cin
#define NBUCKETS 16

typedef __attribute__((ext_vector_type(8))) short s8v;   // 8 x bf16 (4 VGPR)
typedef __attribute__((ext_vector_type(4))) float f4v;   // 4 x f32 acc

__device__ __forceinline__ unsigned short f2bf(float f) {
  unsigned int u = __float_as_uint(f);
  unsigned int r = (u + 0x7fffu + ((u >> 16) & 1u)) >> 16;   // RNE
  return (unsigned short)r;
}

// ---- prep: min/max, sequential bucket cascade, bf16 convert, K-reorder ----
// W2 layout: [hf][co][off*64+cin] bf16  (hf 0 = original, 1 = hashed)
__global__ __launch_bounds__(1024) void hashedconv_prep_kernel(
    const float* __restrict__ W, const float* __restrict__ hashed_w,
    unsigned short* __restrict__ W2) {
  const int NW = COUT * CIN * 9;
  int tid = threadIdx.x;

  float vmin = 1e30f, vmax = -1e30f;
  for (int i = tid; i < NW; i += 1024) {
    float v = W[i];
    vmin = fminf(vmin, v);
    vmax = fmaxf(vmax, v);
  }
  #pragma unroll
  for (int off = 32; off > 0; off >>= 1) {
    vmin = fminf(vmin, __shfl_down(vmin, off, 64));
    vmax = fmaxf(vmax, __shfl_down(vmax, off, 64));
  }
  __shared__ float smin[16], smax[16];
  __shared__ float s_wmin, s_step;
  __shared__ float hv[NBUCKETS];
  int wave = tid >> 6, lane = tid & 63;
  if (lane == 0) { smin[wave] = vmin; smax[wave] = vmax; }
  if (tid < NBUCKETS) hv[tid] = hashed_w[tid];
  __syncthreads();
  if (tid == 0) {
    float m = smin[0], M = smax[0];
    #pragma unroll
    for (int i = 1; i < 16; ++i) { m = fminf(m, smin[i]); M = fmaxf(M, smax[i]); }
    s_wmin = m;
    s_step = (M - m) / (float)NBUCKETS;
  }
  __syncthreads();
  float wmin = s_wmin, step = s_step;

  for (int i = tid; i < NW; i += 1024) {
    float v = W[i];
    int co  = i / 576;
    int rem = i - co * 576;
    int cin = rem / 9;
    int off = rem - cin * 9;
    float h = v;
    #pragma unroll
    for (int b = 0; b < NBUCKETS; ++b) {
      float thr = (float)(b + 1) * step + wmin;
      if (h > thr) h = hv[b];   // sequential in-place semantics
    }
    int oidx = co * KTOT + off * 64 + cin;
    W2[oidx]               = f2bf(v);
    W2[COUT * KTOT + oidx] = f2bf(h);
  }
}

// ---- implicit-GEMM dual conv, bf16 MFMA 16x16x32 ----
// block: 256 thr = 4 waves (2x2), block tile M=128 (all couts of one half)
//        x N=128 pixels (8 rows x 16 cols). wave tile 64x64.
// LDS: xs [180 pixels][64 cin] bf16 (XOR-swizzled), wc [128 co][64 cin] per offset chunk.
__global__ __launch_bounds__(256) void hashedconv_mfma_kernel(
    const float* __restrict__ x, const unsigned short* __restrict__ W2,
    const float* __restrict__ b, const float* __restrict__ b2,
    float* __restrict__ out, size_t out_half) {
  __shared__ __attribute__((aligned(16))) short lds[11520 + 8192];
  short* xs = lds;           // 180*64
  short* wcs = lds + 11520;  // 128*64

  const int tid = threadIdx.x;
  const int bx = blockIdx.x;           // 0..97 : 14 x 7 tiles
  const int n  = blockIdx.y;
  const int hf = blockIdx.z;
  const int ty = bx / 7, tx = bx - ty * 7;
  const int h0 = ty * 8, w0 = tx * 16;

  const int lane = tid & 63;
  const int wv = tid >> 6;
  const int wr  = wv >> 1;   // wave M half (0..1)
  const int wcn = wv & 1;    // wave N half (0..1)
  const int lrow = lane & 15;
  const int g = lane >> 4;   // k-group 0..3

  f4v acc[4][4];
  #pragma unroll
  for (int i = 0; i < 4; ++i)
    #pragma unroll
    for (int j = 0; j < 4; ++j) acc[i][j] = (f4v)(0.f);

  // ---- stage full-depth x tile: 180 pixels x 64 cin (bf16, swizzled) ----
  const float* xn = x + (size_t)n * CIN * HHW * HHW;
  for (int u = tid; u < 1440; u += 256) {       // 180 pix * 8 cin-groups
    int cg = u / 180;
    int pix = u - cg * 180;
    int pyp = pix / 18, pxp = pix - pyp * 18;
    int gh = h0 - 1 + pyp, gw = w0 - 1 + pxp;
    bool inb = (gh >= 0) & (gh < HHW) & (gw >= 0) & (gw < HHW);
    const float* xp = xn + (size_t)(cg * 8) * 12544 + gh * HHW + gw;
    s8v pk;
    #pragma unroll
    for (int c = 0; c < 8; ++c) {
      float v = inb ? xp[(size_t)c * 12544] : 0.f;
      pk[c] = (short)f2bf(v);
    }
    int dst = pix * 64 + ((cg * 8) ^ ((pix & 7) << 3));
    *(s8v*)(xs + dst) = pk;
  }

  const unsigned short* Wh = W2 + (size_t)hf * COUT * KTOT;

  for (int c = 0; c < 9; ++c) {        // offset chunks: K = c*64 .. +64
    // stage weight chunk [128 co][64 cin] (swizzled)
    #pragma unroll
    for (int j = 0; j < 4; ++j) {
      int u = tid + j * 256;           // 0..1023 16B-units
      int row = u >> 3, slot = u & 7;
      s8v v = *(const s8v*)(Wh + (size_t)row * KTOT + c * 64 + slot * 8);
      int dst = row * 64 + ((slot * 8) ^ ((row & 7) << 3));
      *(s8v*)(wcs + dst) = v;
    }
    __syncthreads();

    int dh = c / 3, dw = c - dh * 3;
    #pragma unroll
    for (int kh2 = 0; kh2 < 2; ++kh2) {   // two K=32 steps per chunk
      int kofs = kh2 * 32 + g * 8;        // cin base for this lane
      s8v af[4], bfv[4];
      #pragma unroll
      for (int mt = 0; mt < 4; ++mt) {
        int row = wr * 64 + mt * 16 + lrow;
        af[mt] = *(const s8v*)(wcs + row * 64 + (kofs ^ ((row & 7) << 3)));
      }
      #pragma unroll
      for (int nt = 0; nt < 4; ++nt) {
        int p = wcn * 64 + nt * 16 + lrow;
        int s = ((p >> 4) + dh) * 18 + ((p & 15) + dw);
        bfv[nt] = *(const s8v*)(xs + s * 64 + (kofs ^ ((s & 7) << 3)));
      }
      #pragma unroll
      for (int mt = 0; mt < 4; ++mt)
        #pragma unroll
        for (int nt = 0; nt < 4; ++nt)
          acc[mt][nt] = __builtin_amdgcn_mfma_f32_16x16x32_bf16(
              af[mt], bfv[nt], acc[mt][nt], 0, 0, 0);
    }
    __syncthreads();
  }

  // ---- epilogue: bias + store (D: col=lane&15 -> pixel, row=g*4+r -> cout) ----
  const float* bias = hf ? b2 : b;
  float* obase = out + (size_t)hf * out_half + (size_t)n * COUT * 12544;
  #pragma unroll
  for (int mt = 0; mt < 4; ++mt) {
    #pragma unroll
    for (int r = 0; r < 4; ++r) {
      int co = wr * 64 + mt * 16 + g * 4 + r;
      float bv = bias[co];
      #pragma unroll
      for (int nt = 0; nt < 4; ++nt) {
        int p = wcn * 64 + nt * 16 + lrow;
        int h = h0 + (p >> 4), w = w0 + (p & 15);
        obase[(size_t)co * 12544 + h * HHW + w] = acc[mt][nt][r] + bv;
      }
    }
  }
}

extern "C" void kernel_launch(void* const* d_in, const int* in_sizes, int n_in,
                              void* d_out, int out_size, void* d_ws, size_t ws_size,
                              hipStream_t stream) {
  const float* x      = (const float*)d_in[0];
  const float* W      = (const float*)d_in[1];
  const float* b      = (const float*)d_in[2];
  const float* b2     = (const float*)d_in[3];
  const float* hashed = (const float*)d_in[4];
  float* out = (float*)d_out;
  unsigned short* W2 = (unsigned short*)d_ws;   // 2*128*576 bf16 = 288 KB

  const int N = in_sizes[0] / (CIN * HHW * HHW);
  const size_t out_half = (size_t)N * COUT * HHW * HHW;

  hipLaunchKernelGGL(hashedconv_prep_kernel, dim3(1), dim3(1024), 0, stream,
                     W, hashed, W2);

  dim3 grid(98, N, 2);
  hipLaunchKernelGGL(hashedconv_mfma_kernel, grid, dim3(256), 0, stream,
                     x, W2, b, b2, out, out_half);
}

// Round 3
// 274.006 us; speedup vs baseline: 7.4161x; 1.6751x over previous
//
#include <hip/hip_runtime.h>
#include <stdint.h>

#define CIN 64
#define HHW 112
#define NPIX 12544
#define COUT 128
#define KTOT 576      // 9 offsets * 64 cin
#define NBUCKETS 16

typedef __attribute__((ext_vector_type(8))) short s8v;            // 8 x bf16
typedef __attribute__((ext_vector_type(4))) float f4v;            // 4 x f32
typedef __attribute__((ext_vector_type(8))) unsigned short u8v;

__device__ __forceinline__ unsigned short f2bf(float f) {
  unsigned int u = __float_as_uint(f);
  unsigned int r = (u + 0x7fffu + ((u >> 16) & 1u)) >> 16;   // RNE
  return (unsigned short)r;
}

__device__ __forceinline__ void gload_lds16(const void* g, void* l) {
  __builtin_amdgcn_global_load_lds(
      (const __attribute__((address_space(1))) unsigned int*)g,
      (__attribute__((address_space(3))) unsigned int*)l, 16, 0, 0);
}

// ---- prep: min/max, sequential bucket cascade, bf16 convert, K-reorder ----
// W2 layout: [hf][co][off*64+cin] bf16
__global__ __launch_bounds__(1024) void hashedconv_prep_kernel(
    const float* __restrict__ W, const float* __restrict__ hashed_w,
    unsigned short* __restrict__ W2) {
  const int NW = COUT * CIN * 9;
  int tid = threadIdx.x;
  float vmin = 1e30f, vmax = -1e30f;
  for (int i = tid; i < NW; i += 1024) {
    float v = W[i];
    vmin = fminf(vmin, v);
    vmax = fmaxf(vmax, v);
  }
  #pragma unroll
  for (int off = 32; off > 0; off >>= 1) {
    vmin = fminf(vmin, __shfl_down(vmin, off, 64));
    vmax = fmaxf(vmax, __shfl_down(vmax, off, 64));
  }
  __shared__ float smin[16], smax[16];
  __shared__ float s_wmin, s_step;
  __shared__ float hv[NBUCKETS];
  int wave = tid >> 6, lane = tid & 63;
  if (lane == 0) { smin[wave] = vmin; smax[wave] = vmax; }
  if (tid < NBUCKETS) hv[tid] = hashed_w[tid];
  __syncthreads();
  if (tid == 0) {
    float m = smin[0], M = smax[0];
    #pragma unroll
    for (int i = 1; i < 16; ++i) { m = fminf(m, smin[i]); M = fmaxf(M, smax[i]); }
    s_wmin = m;
    s_step = (M - m) / (float)NBUCKETS;
  }
  __syncthreads();
  float wmin = s_wmin, step = s_step;
  for (int i = tid; i < NW; i += 1024) {
    float v = W[i];
    int co  = i / 576;
    int rem = i - co * 576;
    int cin = rem / 9;
    int off = rem - cin * 9;
    float h = v;
    #pragma unroll
    for (int b = 0; b < NBUCKETS; ++b) {
      float thr = (float)(b + 1) * step + wmin;
      if (h > thr) h = hv[b];
    }
    int oidx = co * KTOT + off * 64 + cin;
    W2[oidx]               = f2bf(v);
    W2[COUT * KTOT + oidx] = f2bf(h);
  }
}

// ---- x: NCHW f32 -> NHWC bf16 ----
__global__ __launch_bounds__(256) void xpose_kernel(
    const float* __restrict__ x, unsigned short* __restrict__ xb) {
  __shared__ unsigned short t[64][264];
  const int n = blockIdx.y, p0 = blockIdx.x * 256, tid = threadIdx.x;
  const float* xp = x + (size_t)n * CIN * NPIX + p0;
  #pragma unroll
  for (int c = 0; c < 64; ++c)
    t[c][tid] = f2bf(xp[(size_t)c * NPIX + tid]);
  __syncthreads();
  unsigned short* ob = xb + ((size_t)n * NPIX + p0) * 64;
  #pragma unroll
  for (int it = 0; it < 8; ++it) {
    int u = it * 256 + tid;            // 2048 16B-units
    int px = u >> 3, slot = u & 7;
    u8v v;
    #pragma unroll
    for (int k = 0; k < 8; ++k) v[k] = t[slot * 8 + k][px];
    *(u8v*)(ob + (size_t)u * 8) = v;
  }
}

// ---- implicit-GEMM dual-launch conv, 16x16 pixel tile, gload_lds staging ----
#define XS_PIXPAD 352
#define XS_SHORTS (XS_PIXPAD * 64)   // 22528
#define WS_SHORTS (COUT * 64)        // 8192

__global__ __launch_bounds__(256, 2) void hashedconv_mfma_kernel(
    const unsigned short* __restrict__ xb, const unsigned short* __restrict__ W2,
    const float* __restrict__ b, const float* __restrict__ b2,
    const unsigned short* __restrict__ zp, float* __restrict__ out,
    size_t out_half) {
  __shared__ __attribute__((aligned(16))) short lds[XS_SHORTS + 2 * WS_SHORTS];
  short* xs = lds;
  short* ws0 = lds + XS_SHORTS;

  const int tid = threadIdx.x;
  const int bx = blockIdx.x;           // 0..48 : 7x7 tiles of 16x16
  const int n  = blockIdx.y;
  const int hf = blockIdx.z;
  const int ty = bx / 7, tx = bx - ty * 7;
  const int h0 = ty * 16, w0 = tx * 16;
  const int lane = tid & 63, wv = tid >> 6;
  const int wr = wv >> 1, wcn = wv & 1;
  const int lrow = lane & 15, g = lane >> 4;

  const unsigned short* Wh = W2 + (size_t)hf * COUT * KTOT;

  // stage x tile: 18x18=324 pixels (padded to 352) x 64 cin, swizzled-source
  #pragma unroll
  for (int it = 0; it < 11; ++it) {
    int u = it * 256 + tid;
    int pix = u >> 3, slot = u & 7;
    int py = pix / 18, px = pix - py * 18;
    int gh = h0 - 1 + py, gw = w0 - 1 + px;
    bool inb = (pix < 324) & (gh >= 0) & (gh < HHW) & (gw >= 0) & (gw < HHW);
    int srcslot = slot ^ (pix & 7);
    const unsigned short* gsrc = inb
        ? xb + (((size_t)n * NPIX + gh * HHW + gw) * 64 + srcslot * 8)
        : zp + srcslot * 8;
    gload_lds16(gsrc, xs + (size_t)(it * 256 + wv * 64) * 8);
  }

  auto stage_w = [&](short* buf, int c) {
    #pragma unroll
    for (int j = 0; j < 4; ++j) {
      int u = j * 256 + tid;           // 1024 16B-units: [128 co][8 slots]
      int row = u >> 3, slot = u & 7;
      int srcslot = slot ^ (row & 7);
      gload_lds16(Wh + (size_t)row * KTOT + c * 64 + srcslot * 8,
                  buf + (size_t)(j * 256 + wv * 64) * 8);
    }
  };

  f4v acc[4][8];
  #pragma unroll
  for (int i = 0; i < 4; ++i)
    #pragma unroll
    for (int j = 0; j < 8; ++j) acc[i][j] = (f4v)(0.f);

  int pyv[8], pxv[8];
  #pragma unroll
  for (int nt = 0; nt < 8; ++nt) {
    int p = wcn * 128 + nt * 16 + lrow;
    pyv[nt] = p >> 4; pxv[nt] = p & 15;
  }

  stage_w(ws0, 0);
  __syncthreads();                     // x + chunk0 weights ready

  int cur = 0;
  for (int c = 0; c < 9; ++c) {
    short* wbuf = ws0 + cur * WS_SHORTS;
    if (c < 8) stage_w(ws0 + (cur ^ 1) * WS_SHORTS, c + 1);  // prefetch
    int dh = c / 3, dw = c - dh * 3;
    #pragma unroll
    for (int kh2 = 0; kh2 < 2; ++kh2) {
      int kofs = kh2 * 32 + g * 8;
      s8v af[4], bfv[8];
      #pragma unroll
      for (int mt = 0; mt < 4; ++mt) {
        int row = wr * 64 + mt * 16 + lrow;
        af[mt] = *(const s8v*)(wbuf + row * 64 + (kofs ^ ((row & 7) << 3)));
      }
      #pragma unroll
      for (int nt = 0; nt < 8; ++nt) {
        int s = (pyv[nt] + dh) * 18 + pxv[nt] + dw;
        bfv[nt] = *(const s8v*)(xs + s * 64 + (kofs ^ ((s & 7) << 3)));
      }
      #pragma unroll
      for (int mt = 0; mt < 4; ++mt)
        #pragma unroll
        for (int nt = 0; nt < 8; ++nt)
          acc[mt][nt] = __builtin_amdgcn_mfma_f32_16x16x32_bf16(
              af[mt], bfv[nt], acc[mt][nt], 0, 0, 0);
    }
    __syncthreads();                   // drains prefetch too (vmcnt at barrier)
    cur ^= 1;
  }

  const float* bias = hf ? b2 : b;
  float* obase = out + (size_t)hf * out_half + (size_t)n * COUT * NPIX;
  #pragma unroll
  for (int mt = 0; mt < 4; ++mt) {
    #pragma unroll
    for (int r = 0; r < 4; ++r) {
      int co = wr * 64 + mt * 16 + g * 4 + r;
      float bv = bias[co];
      #pragma unroll
      for (int nt = 0; nt < 8; ++nt) {
        int p = wcn * 128 + nt * 16 + lrow;
        int h = h0 + (p >> 4), w = w0 + (p & 15);
        obase[(size_t)co * NPIX + h * HHW + w] = acc[mt][nt][r] + bv;
      }
    }
  }
}

// ---- fallback (round-2 kernel, reg-staged from fp32 x) if ws too small ----
__global__ __launch_bounds__(256) void hashedconv_fb_kernel(
    const float* __restrict__ x, const unsigned short* __restrict__ W2,
    const float* __restrict__ b, const float* __restrict__ b2,
    float* __restrict__ out, size_t out_half) {
  __shared__ __attribute__((aligned(16))) short lds[11520 + 8192];
  short* xs = lds;
  short* wcs = lds + 11520;
  const int tid = threadIdx.x;
  const int bx = blockIdx.x;
  const int n  = blockIdx.y;
  const int hf = blockIdx.z;
  const int ty = bx / 7, tx = bx - ty * 7;
  const int h0 = ty * 8, w0 = tx * 16;
  const int lane = tid & 63, wv = tid >> 6;
  const int wr = wv >> 1, wcn = wv & 1;
  const int lrow = lane & 15, g = lane >> 4;
  f4v acc[4][4];
  #pragma unroll
  for (int i = 0; i < 4; ++i)
    #pragma unroll
    for (int j = 0; j < 4; ++j) acc[i][j] = (f4v)(0.f);
  const float* xn = x + (size_t)n * CIN * NPIX;
  for (int u = tid; u < 1440; u += 256) {
    int cg = u / 180;
    int pix = u - cg * 180;
    int pyp = pix / 18, pxp = pix - pyp * 18;
    int gh = h0 - 1 + pyp, gw = w0 - 1 + pxp;
    bool inb = (gh >= 0) & (gh < HHW) & (gw >= 0) & (gw < HHW);
    const float* xp = xn + (size_t)(cg * 8) * NPIX + gh * HHW + gw;
    s8v pk;
    #pragma unroll
    for (int cc = 0; cc < 8; ++cc) {
      float v = inb ? xp[(size_t)cc * NPIX] : 0.f;
      pk[cc] = (short)f2bf(v);
    }
    *(s8v*)(xs + pix * 64 + ((cg * 8) ^ ((pix & 7) << 3))) = pk;
  }
  const unsigned short* Wh = W2 + (size_t)hf * COUT * KTOT;
  for (int c = 0; c < 9; ++c) {
    #pragma unroll
    for (int j = 0; j < 4; ++j) {
      int u = tid + j * 256;
      int row = u >> 3, slot = u & 7;
      s8v v = *(const s8v*)(Wh + (size_t)row * KTOT + c * 64 + slot * 8);
      *(s8v*)(wcs + row * 64 + ((slot * 8) ^ ((row & 7) << 3))) = v;
    }
    __syncthreads();
    int dh = c / 3, dw = c - dh * 3;
    #pragma unroll
    for (int kh2 = 0; kh2 < 2; ++kh2) {
      int kofs = kh2 * 32 + g * 8;
      s8v af[4], bfv[4];
      #pragma unroll
      for (int mt = 0; mt < 4; ++mt) {
        int row = wr * 64 + mt * 16 + lrow;
        af[mt] = *(const s8v*)(wcs + row * 64 + (kofs ^ ((row & 7) << 3)));
      }
      #pragma unroll
      for (int nt = 0; nt < 4; ++nt) {
        int p = wcn * 64 + nt * 16 + lrow;
        int s = ((p >> 4) + dh) * 18 + ((p & 15) + dw);
        bfv[nt] = *(const s8v*)(xs + s * 64 + (kofs ^ ((s & 7) << 3)));
      }
      #pragma unroll
      for (int mt = 0; mt < 4; ++mt)
        #pragma unroll
        for (int nt = 0; nt < 4; ++nt)
          acc[mt][nt] = __builtin_amdgcn_mfma_f32_16x16x32_bf16(
              af[mt], bfv[nt], acc[mt][nt], 0, 0, 0);
    }
    __syncthreads();
  }
  const float* bias = hf ? b2 : b;
  float* obase = out + (size_t)hf * out_half + (size_t)n * COUT * NPIX;
  #pragma unroll
  for (int mt = 0; mt < 4; ++mt) {
    #pragma unroll
    for (int r = 0; r < 4; ++r) {
      int co = wr * 64 + mt * 16 + g * 4 + r;
      float bv = bias[co];
      #pragma unroll
      for (int nt = 0; nt < 4; ++nt) {
        int p = wcn * 64 + nt * 16 + lrow;
        int h = h0 + (p >> 4), w = w0 + (p & 15);
        obase[(size_t)co * NPIX + h * HHW + w] = acc[mt][nt][r] + bv;
      }
    }
  }
}

extern "C" void kernel_launch(void* const* d_in, const int* in_sizes, int n_in,
                              void* d_out, int out_size, void* d_ws, size_t ws_size,
                              hipStream_t stream) {
  const float* x      = (const float*)d_in[0];
  const float* W      = (const float*)d_in[1];
  const float* b      = (const float*)d_in[2];
  const float* b2     = (const float*)d_in[3];
  const float* hashed = (const float*)d_in[4];
  float* out = (float*)d_out;

  const int N = in_sizes[0] / (CIN * NPIX);
  const size_t out_half = (size_t)N * COUT * NPIX;
  const size_t XB_SHORTS = (size_t)N * NPIX * 64;
  const size_t need = (XB_SHORTS + 2 * COUT * KTOT) * 2 + 256;

  if (ws_size >= need) {
    unsigned short* xb = (unsigned short*)d_ws;
    unsigned short* W2 = xb + XB_SHORTS;
    unsigned short* zp = W2 + 2 * COUT * KTOT;
    hipMemsetAsync(zp, 0, 256, stream);
    hipLaunchKernelGGL(hashedconv_prep_kernel, dim3(1), dim3(1024), 0, stream,
                       W, hashed, W2);
    hipLaunchKernelGGL(xpose_kernel, dim3(NPIX / 256, N), dim3(256), 0, stream,
                       x, xb);
    hipLaunchKernelGGL(hashedconv_mfma_kernel, dim3(49, N, 2), dim3(256), 0,
                       stream, xb, W2, b, b2, zp, out, out_half);
  } else {
    unsigned short* W2 = (unsigned short*)d_ws;
    hipLaunchKernelGGL(hashedconv_prep_kernel, dim3(1), dim3(1024), 0, stream,
                       W, hashed, W2);
    hipLaunchKernelGGL(hashedconv_fb_kernel, dim3(98, N, 2), dim3(256), 0,
                       stream, x, W2, b, b2, out, out_half);
  }
}